// Round 14
// baseline (868.113 us; speedup 1.0000x reference)
//
#include <hip/hip_runtime.h>
#include <stdint.h>
#include <math.h>

// MetropolisHastingsSampler: 2176-step serial MH chain, D=512, H=1024.
// R14: SINGLE fused kernel. Blocks 1..255 are producers: block b owns rows
// b-1, b-1+255, ... (cyclic; ~9 rows). Per row: bit-exact threefry RNG ->
// A row (+U), then f64 matvec Z row = A row @ W1 (operand-identical
// association to R13's gemm64 -> Z bit-identical). Publish: release-flag1
// after first row, release-flag2 after all rows; then DVFS-filler spin.
// Block 0 = chain (R13 structure, bit-identical math), guarded by a
// ballot-vectorized frontier scan over the flags (acquire). Chain consumes
// ~3 rows/us; producers make >30 rows/us -> producer phase fully hidden.
// Coherence: consumer first-touches each Z/A/U line only after acquire that
// follows the producer's release; guard leads consumption by 32 rows
// (covers the 64B scalar-cache line span of U reads).
// Workspace: A(2184x512 f32) | Z(2184x1024 f32) | U(2184) | flag1[256] |
// flag2[256] | cflag  ~= 12.8 MiB.

#define T_TOTAL 2176
#define NITER   1088
#define NROWS   2177
#define NBURN   128
#define DDIM    512
#define HDIM    1024
#define FLAG_DONE 0x13572468u

// ---------------- threefry2x32 (JAX-exact) ----------------
__device__ __forceinline__ uint2 tf2x32(uint32_t k0, uint32_t k1,
                                        uint32_t x0, uint32_t x1) {
  uint32_t ks2 = k0 ^ k1 ^ 0x1BD11BDAu;
  x0 += k0; x1 += k1;
#define TF_R(r) { x0 += x1; x1 = (x1 << (r)) | (x1 >> (32 - (r))); x1 ^= x0; }
  TF_R(13) TF_R(15) TF_R(26) TF_R(6)
  x0 += k1;  x1 += ks2 + 1u;
  TF_R(17) TF_R(29) TF_R(16) TF_R(24)
  x0 += ks2; x1 += k0 + 2u;
  TF_R(13) TF_R(15) TF_R(26) TF_R(6)
  x0 += k0;  x1 += k1 + 3u;
  TF_R(17) TF_R(29) TF_R(16) TF_R(24)
  x0 += k1;  x1 += ks2 + 4u;
  TF_R(13) TF_R(15) TF_R(26) TF_R(6)
  x0 += ks2; x1 += k0 + 5u;
#undef TF_R
  return make_uint2(x0, x1);
}

// ---------------- XLA ErfInv f32 (Giles polynomial) ----------------
__device__ __forceinline__ float erfinv_xla(float x) {
  float w = -log1pf(-x * x);
  float p;
  if (w < 5.0f) {
    w = w - 2.5f;
    p = 2.81022636e-08f;
    p = fmaf(p, w, 3.43273939e-07f);
    p = fmaf(p, w, -3.5233877e-06f);
    p = fmaf(p, w, -4.39150654e-06f);
    p = fmaf(p, w, 0.00021858087f);
    p = fmaf(p, w, -0.00125372503f);
    p = fmaf(p, w, -0.00417768164f);
    p = fmaf(p, w, 0.246640727f);
    p = fmaf(p, w, 1.50140941f);
  } else {
    w = sqrtf(w) - 3.0f;
    p = -0.000200214257f;
    p = fmaf(p, w, 0.000100950558f);
    p = fmaf(p, w, 0.00134934322f);
    p = fmaf(p, w, -0.00367342844f);
    p = fmaf(p, w, 0.00573950773f);
    p = fmaf(p, w, -0.0076224613f);
    p = fmaf(p, w, 0.00943887047f);
    p = fmaf(p, w, 1.00167406f);
    p = fmaf(p, w, 2.83297682f);
  }
  return p * x;
}

__device__ __forceinline__ float normal_from_bits(uint32_t bits) {
  const float lo = -0.99999994f;  // -(1 - 2^-24)
  float u01 = __uint_as_float(0x3f800000u | (bits >> 9)) - 1.0f;
  float v = u01 * 2.0f + lo;
  v = fmaxf(lo, v);
  return 1.41421356237309515f * erfinv_xla(v);
}

// ---------------- fast tanh via hardware exp2 ----------------
__device__ __forceinline__ float tanh_fast(float x) {
  float a = x * 2.88539008177792681472f;       // 2*log2(e)
#if __has_builtin(__builtin_amdgcn_exp2f)
  float e = __builtin_amdgcn_exp2f(a);
#else
  float e = exp2f(a);
#endif
  float r = __builtin_amdgcn_rcpf(e + 1.0f);
  return fmaf(-2.0f, r, 1.0f);
}

// ---------------- DPP wave64 sum-reduce (result in lane 63) ----------------
#define DPP_ADD(v, ctrl)                                                     \
  v += __int_as_float(__builtin_amdgcn_update_dpp(                           \
      0, __float_as_int(v), (ctrl), 0xF, 0xF, true))

__device__ __forceinline__ float wave_reduce_to_last(float v) {
  DPP_ADD(v, 0xB1);   // quad_perm xor1
  DPP_ADD(v, 0x4E);   // quad_perm xor2
  DPP_ADD(v, 0x141);  // row_half_mirror
  DPP_ADD(v, 0x140);  // row_mirror -> row16 totals
  DPP_ADD(v, 0x142);  // row_bcast15
  DPP_ADD(v, 0x143);  // row_bcast31 -> lane 63 wave total
  return v;
}

// Execution barrier with LDS-visibility only (no vmcnt drain).
#define BAR() asm volatile("s_waitcnt lgkmcnt(0)\n\ts_barrier" ::: "memory")

// ---------------- frontier scan (chain block; uniform) ----------------
// flag1[b]: block b's first row (row b-1) done. flag2[b]: all rows done.
// rows 0..254: row r owned by block r+1 (its first row). rows >=255: row r
// owned by block (r%255)+1; covered by that block's flag2 (conservative).
// Returns consecutive-ready row count (prefix).
__device__ __forceinline__ int frontier_scan(
    const unsigned* flag1, const unsigned* flag2, int tid, int lane, int wid,
    unsigned long long (*sball)[4]) {
  unsigned f1 = FLAG_DONE, f2 = FLAG_DONE;
  if (tid >= 1) {
    f1 = __hip_atomic_load(flag1 + tid, __ATOMIC_ACQUIRE,
                           __HIP_MEMORY_SCOPE_AGENT);
    f2 = __hip_atomic_load(flag2 + tid, __ATOMIC_ACQUIRE,
                           __HIP_MEMORY_SCOPE_AGENT);
  }
  unsigned long long m1 = __ballot(f1 == FLAG_DONE);
  unsigned long long m2 = __ballot(f2 == FLAG_DONE);
  if (lane == 0) { sball[0][wid] = m1; sball[1][wid] = m2; }
  __syncthreads();
  int P1 = 0, P2 = 0; bool s1 = false, s2 = false;
#pragma unroll
  for (int w = 0; w < 4; ++w) {
    unsigned long long v1 = sball[0][w], v2 = sball[1][w];
    if (!s1) { int c = (~v1 == 0ull) ? 64 : __builtin_ctzll(~v1); P1 += c; s1 = (c < 64); }
    if (!s2) { int c = (~v2 == 0ull) ? 64 : __builtin_ctzll(~v2); P2 += c; s2 = (c < 64); }
  }
  __syncthreads();
  int p1b = P1 - 1, p2b = P2 - 1;   // consecutive done blocks from b=1
  return (p1b < 255) ? p1b : ((p2b < 255) ? 255 + p2b : NROWS);
}

// ---------------- producer: RNG one row into LDS + global ----------------
__device__ __forceinline__ void rng_row(int r, int tid,
                                        const float* __restrict__ x0,
                                        float* __restrict__ A,
                                        float* __restrict__ U,
                                        float* AsRow) {
  float v0, v1;
  if (r == 0) {
    v0 = x0[tid]; v1 = x0[tid + 256];
  } else {
    uint32_t t = (uint32_t)(r - 1);
    uint2 kt = tf2x32(0u, 1u, 0u, t);
    uint2 kn = tf2x32(kt.x, kt.y, 0u, 0u);
    uint2 e0 = tf2x32(kn.x, kn.y, 0u, (uint32_t)tid);
    uint2 e1 = tf2x32(kn.x, kn.y, 0u, (uint32_t)(tid + 256));
    v0 = normal_from_bits(e0.x ^ e0.y) * 0.1f;
    v1 = normal_from_bits(e1.x ^ e1.y) * 0.1f;
    if (tid == 0) {
      uint2 ku = tf2x32(kt.x, kt.y, 0u, 1u);
      uint2 eu = tf2x32(ku.x, ku.y, 0u, 0u);
      U[t] = __uint_as_float(0x3f800000u | ((eu.x ^ eu.y) >> 9)) - 1.0f;
    }
  }
  AsRow[tid] = v0; AsRow[tid + 256] = v1;
  A[(size_t)r * DDIM + tid]       = v0;
  A[(size_t)r * DDIM + tid + 256] = v1;
}

// ---------------- THE fused kernel ----------------
__global__ void __launch_bounds__(256) mega_kernel(
    const float* __restrict__ x0, const float* __restrict__ W1,
    const float* __restrict__ b1, const float* __restrict__ W2,
    const float* __restrict__ b2, float* __restrict__ out,
    float* __restrict__ A, float* __restrict__ Z, float* __restrict__ U,
    unsigned* flag1, unsigned* flag2, unsigned* cflag) {
  const int tid = threadIdx.x;
  __shared__ float As[9][512];                       // producer row staging
  __shared__ __align__(16) float wsum[2][3][4];      // chain partials
  __shared__ unsigned long long sball[2][4];         // frontier scan

  if (blockIdx.x != 0) {
    // =================== PRODUCER (blocks 1..255) ===================
    const int b = blockIdx.x;
    const int nown = (b <= 137) ? 9 : 8;             // rows b-1 + 255*j

    // phase 1: first row (row b-1) -> flag1
    rng_row(b - 1, tid, x0, A, U, As[0]);
    __syncthreads();
    {
      double acc[4] = {0.0, 0.0, 0.0, 0.0};
      for (int d = 0; d < 512; d += 4) {
        double w[4][4];
#pragma unroll
        for (int j = 0; j < 4; ++j)
#pragma unroll
          for (int c = 0; c < 4; ++c)
            w[j][c] = (double)W1[(size_t)(d + j) * 1024 + tid + 256 * c];
        const float4 a4 = *(const float4*)&As[0][d];
        double a0 = (double)a4.x, a1 = (double)a4.y;
        double a2 = (double)a4.z, a3 = (double)a4.w;
#pragma unroll
        for (int c = 0; c < 4; ++c)
          acc[c] += (a0 * w[0][c] + a1 * w[1][c]) +
                    (a2 * w[2][c] + a3 * w[3][c]);
      }
#pragma unroll
      for (int c = 0; c < 4; ++c)
        Z[(size_t)(b - 1) * 1024 + tid + 256 * c] = (float)acc[c];
    }
    __syncthreads();                                 // drains vmcnt too
    if (tid == 0)
      __hip_atomic_store(flag1 + b, FLAG_DONE, __ATOMIC_RELEASE,
                         __HIP_MEMORY_SCOPE_AGENT);

    // phase 2: remaining rows -> flag2
    for (int j = 1; j < nown; ++j)
      rng_row((b - 1) + 255 * j, tid, x0, A, U, As[j]);
    if (b == 1 && tid < 8) U[2176 + tid] = 0.5f;     // U padding
    __syncthreads();
    for (int j0 = 1; j0 < 9; j0 += 4) {
      double acc[4][4];
#pragma unroll
      for (int q = 0; q < 4; ++q)
#pragma unroll
        for (int c = 0; c < 4; ++c) acc[q][c] = 0.0;
      for (int d = 0; d < 512; d += 4) {
        double w[4][4];
#pragma unroll
        for (int j = 0; j < 4; ++j)
#pragma unroll
          for (int c = 0; c < 4; ++c)
            w[j][c] = (double)W1[(size_t)(d + j) * 1024 + tid + 256 * c];
#pragma unroll
        for (int q = 0; q < 4; ++q) {
          const float4 a4 = *(const float4*)&As[j0 + q][d];
          double a0 = (double)a4.x, a1 = (double)a4.y;
          double a2 = (double)a4.z, a3 = (double)a4.w;
#pragma unroll
          for (int c = 0; c < 4; ++c)
            acc[q][c] += (a0 * w[0][c] + a1 * w[1][c]) +
                         (a2 * w[2][c] + a3 * w[3][c]);
        }
      }
#pragma unroll
      for (int q = 0; q < 4; ++q) {
        int j = j0 + q;
        if (j < nown) {
          size_t r = (size_t)(b - 1) + 255 * j;
#pragma unroll
          for (int c = 0; c < 4; ++c)
            Z[r * 1024 + tid + 256 * c] = (float)acc[q][c];
        }
      }
    }
    __syncthreads();                                 // drains vmcnt
    if (tid == 0)
      __hip_atomic_store(flag2 + b, FLAG_DONE, __ATOMIC_RELEASE,
                         __HIP_MEMORY_SCOPE_AGENT);

    // DVFS-keeper filler: bounded spin until chain done.
    float acc = (float)tid * 1.0e-6f;
    for (int i = 0; i < 16000; ++i) {
#pragma unroll
      for (int jj = 0; jj < 64; ++jj) acc = fmaf(acc, 0.99999988f, 1.0e-7f);
      unsigned f = __hip_atomic_load(cflag, __ATOMIC_RELAXED,
                                     __HIP_MEMORY_SCOPE_AGENT);
      if (f == FLAG_DONE) break;
    }
    if (acc == 123456.75f && tid == 1023) out[0] = acc;  // never true
    return;
  }

  // =================== CHAIN (block 0) ===================
  const int lane = tid & 63;
  const int wid = tid >> 6;

  int rows_safe = 0;
  while (rows_safe < 40) {
    rows_safe = frontier_scan(flag1, flag2, tid, lane, wid, sball);
    if (rows_safe < 40) __builtin_amdgcn_s_sleep(32);
  }

  const float4* Zv = (const float4*)Z;   // 256 float4 per H-row
  const float2* Av = (const float2*)A;   // 256 float2 per D-row

  const float4 w2v = ((const float4*)W2)[tid];
  const float4 b1v = ((const float4*)b1)[tid];
  const float b2v = b2[0];

  float4 z0r = Zv[tid];
  float4 z1r = Zv[256 + tid];
  float4 z2r = Zv[512 + tid];
  float4 zA0 = Zv[3 * 256 + tid], zB0 = Zv[4 * 256 + tid];
  float4 zA1 = Zv[5 * 256 + tid], zB1 = Zv[6 * 256 + tid];
  float2 dAa0 = Av[1 * 256 + tid], dAb0 = Av[2 * 256 + tid];
  float2 dAa1 = Av[3 * 256 + tid], dAb1 = Av[4 * 256 + tid];

  double Y0 = (double)z0r.x + (double)b1v.x;
  double Y1 = (double)z0r.y + (double)b1v.y;
  double Y2 = (double)z0r.z + (double)b1v.z;
  double Y3 = (double)z0r.w + (double)b1v.w;

  float xa = x0[2 * tid], xb = x0[2 * tid + 1];

  {
    float g0 = tanh_fast((float)Y0);
    float g1 = tanh_fast((float)Y1);
    float g2 = tanh_fast((float)Y2);
    float g3 = tanh_fast((float)Y3);
    float tm = fmaf(g3, w2v.w, fmaf(g2, w2v.z, fmaf(g1, w2v.y, g0 * w2v.x)));
    tm = wave_reduce_to_last(tm);
    if (lane == 63) wsum[1][0][wid] = tm;
  }
  __syncthreads();
  float p;
  {
    const float4 pp = *(const float4*)wsum[1][0];
    float m0 = ((pp.x + pp.y) + (pp.z + pp.w)) + b2v;
    p = m0 * m0;
  }
  float um1 = U[0] * (p + 1e-12f);
  float u2c = U[1];

  double Ya0 = Y0 + (double)z1r.x, Ya1 = Y1 + (double)z1r.y;
  double Ya2 = Y2 + (double)z1r.z, Ya3 = Y3 + (double)z1r.w;
  double Yb0 = Y0 + (double)z2r.x, Yb1 = Y1 + (double)z2r.y;
  double Yb2 = Y2 + (double)z2r.z, Yb3 = Y3 + (double)z2r.w;
  double Yc0 = Ya0 + (double)z2r.x, Yc1 = Ya1 + (double)z2r.y;
  double Yc2 = Ya2 + (double)z2r.z, Yc3 = Ya3 + (double)z2r.w;
  {
    float a0 = tanh_fast((float)Ya0), a1 = tanh_fast((float)Ya1);
    float a2 = tanh_fast((float)Ya2), a3 = tanh_fast((float)Ya3);
    float b0 = tanh_fast((float)Yb0), b1_ = tanh_fast((float)Yb1);
    float b2_ = tanh_fast((float)Yb2), b3 = tanh_fast((float)Yb3);
    float c0 = tanh_fast((float)Yc0), c1 = tanh_fast((float)Yc1);
    float c2 = tanh_fast((float)Yc2), c3 = tanh_fast((float)Yc3);
    float tA = fmaf(a3, w2v.w, fmaf(a2, w2v.z, fmaf(a1, w2v.y, a0 * w2v.x)));
    float tB = fmaf(b3, w2v.w, fmaf(b2_, w2v.z, fmaf(b1_, w2v.y, b0 * w2v.x)));
    float tC = fmaf(c3, w2v.w, fmaf(c2, w2v.z, fmaf(c1, w2v.y, c0 * w2v.x)));
    tA = wave_reduce_to_last(tA);
    tB = wave_reduce_to_last(tB);
    tC = wave_reduce_to_last(tC);
    if (lane == 63) {
      wsum[0][0][wid] = tA;
      wsum[0][1][wid] = tB;
      wsum[0][2][wid] = tC;
    }
  }
  __syncthreads();

#define ITER(k, PAR, ZAB, ZBB, DAB, DBB)                                     \
  {                                                                          \
    int nd = 2 * (k) + 32; if (nd > NROWS) nd = NROWS;                       \
    while (rows_safe < nd) {                                                 \
      rows_safe = frontier_scan(flag1, flag2, tid, lane, wid, sball);        \
      if (rows_safe < nd) __builtin_amdgcn_s_sleep(16);                      \
    }                                                                        \
    float u1n = U[2 * (k) + 2];                                              \
    float u2n = U[2 * (k) + 3];                                              \
    const float4 e1 = *(const float4*)wsum[PAR][0];                          \
    const float4 e2 = *(const float4*)wsum[PAR][1];                          \
    const float4 e3 = *(const float4*)wsum[PAR][2];                          \
    float m1 = ((e1.x + e1.y) + (e1.z + e1.w)) + b2v;                        \
    float q1 = m1 * m1;                                                      \
    bool a1v = um1 < q1;                                                     \
    float p1 = a1v ? q1 : p;                                                 \
    float um2 = u2c * (p1 + 1e-12f);                                         \
    float m2v = ((e2.x + e2.y) + (e2.z + e2.w)) + b2v;                       \
    float m3v = ((e3.x + e3.y) + (e3.z + e3.w)) + b2v;                       \
    float m23 = a1v ? m3v : m2v;                                             \
    float q23 = m23 * m23;                                                   \
    bool a2v = um2 < q23;                                                    \
    p = a2v ? q23 : p1;                                                      \
    float xat = a1v ? xa + DAB.x : xa;                                       \
    float xbt = a1v ? xb + DAB.y : xb;                                       \
    xa = a2v ? xat + DBB.x : xat;                                            \
    xb = a2v ? xbt + DBB.y : xbt;                                            \
    if ((k) >= 64) {                                                         \
      float2 o1; o1.x = xat; o1.y = xbt;                                     \
      *(float2*)(out + (size_t)(2 * (k) - NBURN) * DDIM + 2 * tid) = o1;     \
      float2 o2; o2.x = xa; o2.y = xb;                                       \
      *(float2*)(out + (size_t)(2 * (k) + 1 - NBURN) * DDIM + 2 * tid) = o2; \
    }                                                                        \
    DAB = Av[(size_t)(2 * (k) + 5) * 256 + tid];                             \
    DBB = Av[(size_t)(2 * (k) + 6) * 256 + tid];                             \
    Y0 = a1v ? (a2v ? Yc0 : Ya0) : (a2v ? Yb0 : Y0);                         \
    Y1 = a1v ? (a2v ? Yc1 : Ya1) : (a2v ? Yb1 : Y1);                         \
    Y2 = a1v ? (a2v ? Yc2 : Ya2) : (a2v ? Yb2 : Y2);                         \
    Y3 = a1v ? (a2v ? Yc3 : Ya3) : (a2v ? Yb3 : Y3);                         \
    Ya0 = Y0 + (double)ZAB.x;  Ya1 = Y1 + (double)ZAB.y;                     \
    Ya2 = Y2 + (double)ZAB.z;  Ya3 = Y3 + (double)ZAB.w;                     \
    Yb0 = Y0 + (double)ZBB.x;  Yb1 = Y1 + (double)ZBB.y;                     \
    Yb2 = Y2 + (double)ZBB.z;  Yb3 = Y3 + (double)ZBB.w;                     \
    Yc0 = Ya0 + (double)ZBB.x; Yc1 = Ya1 + (double)ZBB.y;                    \
    Yc2 = Ya2 + (double)ZBB.z; Yc3 = Ya3 + (double)ZBB.w;                    \
    ZAB = Zv[(size_t)(2 * (k) + 7) * 256 + tid];                             \
    ZBB = Zv[(size_t)(2 * (k) + 8) * 256 + tid];                             \
    float ga0 = tanh_fast((float)Ya0), ga1 = tanh_fast((float)Ya1);          \
    float ga2 = tanh_fast((float)Ya2), ga3 = tanh_fast((float)Ya3);          \
    float gb0 = tanh_fast((float)Yb0), gb1 = tanh_fast((float)Yb1);          \
    float gb2 = tanh_fast((float)Yb2), gb3 = tanh_fast((float)Yb3);          \
    float gc0 = tanh_fast((float)Yc0), gc1 = tanh_fast((float)Yc1);          \
    float gc2 = tanh_fast((float)Yc2), gc3 = tanh_fast((float)Yc3);          \
    float tA = fmaf(ga3, w2v.w, fmaf(ga2, w2v.z, fmaf(ga1, w2v.y, ga0 * w2v.x))); \
    float tB = fmaf(gb3, w2v.w, fmaf(gb2, w2v.z, fmaf(gb1, w2v.y, gb0 * w2v.x))); \
    float tC = fmaf(gc3, w2v.w, fmaf(gc2, w2v.z, fmaf(gc1, w2v.y, gc0 * w2v.x))); \
    tA = wave_reduce_to_last(tA);                                            \
    tB = wave_reduce_to_last(tB);                                            \
    tC = wave_reduce_to_last(tC);                                            \
    if (lane == 63) {                                                        \
      wsum[(PAR) ^ 1][0][wid] = tA;                                          \
      wsum[(PAR) ^ 1][1][wid] = tB;                                          \
      wsum[(PAR) ^ 1][2][wid] = tC;                                          \
    }                                                                        \
    um1 = u1n * (p + 1e-12f);                                                \
    u2c = u2n;                                                               \
    BAR();                                                                   \
  }

  for (int k = 0; k < NITER; k += 2) {
    ITER(k,     0, zA0, zB0, dAa0, dAb0);
    ITER(k + 1, 1, zA1, zB1, dAa1, dAb1);
  }
#undef ITER

  if (tid == 0)
    __hip_atomic_store(cflag, FLAG_DONE, __ATOMIC_RELAXED,
                       __HIP_MEMORY_SCOPE_AGENT);
}

extern "C" void kernel_launch(void* const* d_in, const int* in_sizes, int n_in,
                              void* d_out, int out_size, void* d_ws, size_t ws_size,
                              hipStream_t stream) {
  const float* x0 = (const float*)d_in[0];
  const float* W1 = (const float*)d_in[1];
  const float* b1 = (const float*)d_in[2];
  const float* W2 = (const float*)d_in[3];
  const float* b2 = (const float*)d_in[4];
  float* out = (float*)d_out;

  char* ws = (char*)d_ws;
  // A: 2184x512 f32 = 4,472,832 | Z: 2184x1024 f32 = 8,945,664 |
  // U: 2184 f32 = 8,736 | flag1: 1024 | flag2: 1024 | cflag: 4
  float* A = (float*)ws;
  float* Z = (float*)(ws + 4472832);
  float* U = (float*)(ws + 4472832 + 8945664);
  unsigned* flag1 = (unsigned*)(ws + 4472832 + 8945664 + 8736);
  unsigned* flag2 = flag1 + 256;
  unsigned* cflag = flag2 + 256;

  mega_kernel<<<256, 256, 0, stream>>>(x0, W1, b1, W2, b2, out,
                                       A, Z, U, flag1, flag2, cflag);
}

// Round 15
// 817.445 us; speedup vs baseline: 1.0620x; 1.0620x over previous
//
#include <hip/hip_runtime.h>
#include <stdint.h>
#include <math.h>

// MetropolisHastingsSampler: 2176-step serial MH chain, D=512, H=1024.
//   R15 = R13 (best measured: 837.6us) with ONE change: gemm64 retiled to
//   546 blocks x 512 thr (4 rows x 2 cols/thread). Row-independent, same
//   d-loop association -> Z bit-identical; halves the 273-block tail
//   imbalance (17 CUs ran 2 blocks while 239 idled).
//   K1: RNG (bit-exact JAX threefry, partitionable) -> A (f32) + A64 (f64
//       copies, same values) + U.
//   K2: Z = A64 @ W1, f64 accumulate (cvt-free inner loop).
//   K3: chain (256 thr, 2 steps/barrier, 3-candidate speculation) +
//       DVFS-keeper fillers. R14's producer-consumer fusion regressed
//       (868 vs 837) with ~80us unexplained -> reverted.
// Workspace: A | Z | U | flag | A64  ~= 22.4 MiB (fallback if ws too small).

#define T_TOTAL 2176
#define NITER   1088
#define NROWS   2177
#define NBURN   128
#define DDIM    512
#define HDIM    1024
#define DONE_FLAG 0x13572468u

// ---------------- threefry2x32 (JAX-exact) ----------------
__device__ __forceinline__ uint2 tf2x32(uint32_t k0, uint32_t k1,
                                        uint32_t x0, uint32_t x1) {
  uint32_t ks2 = k0 ^ k1 ^ 0x1BD11BDAu;
  x0 += k0; x1 += k1;
#define TF_R(r) { x0 += x1; x1 = (x1 << (r)) | (x1 >> (32 - (r))); x1 ^= x0; }
  TF_R(13) TF_R(15) TF_R(26) TF_R(6)
  x0 += k1;  x1 += ks2 + 1u;
  TF_R(17) TF_R(29) TF_R(16) TF_R(24)
  x0 += ks2; x1 += k0 + 2u;
  TF_R(13) TF_R(15) TF_R(26) TF_R(6)
  x0 += k0;  x1 += k1 + 3u;
  TF_R(17) TF_R(29) TF_R(16) TF_R(24)
  x0 += k1;  x1 += ks2 + 4u;
  TF_R(13) TF_R(15) TF_R(26) TF_R(6)
  x0 += ks2; x1 += k0 + 5u;
#undef TF_R
  return make_uint2(x0, x1);
}

// ---------------- XLA ErfInv f32 (Giles polynomial) ----------------
__device__ __forceinline__ float erfinv_xla(float x) {
  float w = -log1pf(-x * x);
  float p;
  if (w < 5.0f) {
    w = w - 2.5f;
    p = 2.81022636e-08f;
    p = fmaf(p, w, 3.43273939e-07f);
    p = fmaf(p, w, -3.5233877e-06f);
    p = fmaf(p, w, -4.39150654e-06f);
    p = fmaf(p, w, 0.00021858087f);
    p = fmaf(p, w, -0.00125372503f);
    p = fmaf(p, w, -0.00417768164f);
    p = fmaf(p, w, 0.246640727f);
    p = fmaf(p, w, 1.50140941f);
  } else {
    w = sqrtf(w) - 3.0f;
    p = -0.000200214257f;
    p = fmaf(p, w, 0.000100950558f);
    p = fmaf(p, w, 0.00134934322f);
    p = fmaf(p, w, -0.00367342844f);
    p = fmaf(p, w, 0.00573950773f);
    p = fmaf(p, w, -0.0076224613f);
    p = fmaf(p, w, 0.00943887047f);
    p = fmaf(p, w, 1.00167406f);
    p = fmaf(p, w, 2.83297682f);
  }
  return p * x;
}

__device__ __forceinline__ float normal_from_bits(uint32_t bits) {
  const float lo = -0.99999994f;  // -(1 - 2^-24)
  float u01 = __uint_as_float(0x3f800000u | (bits >> 9)) - 1.0f;
  float v = u01 * 2.0f + lo;
  v = fmaxf(lo, v);
  return 1.41421356237309515f * erfinv_xla(v);
}

// ---------------- fast tanh via hardware exp2 ----------------
__device__ __forceinline__ float tanh_fast(float x) {
  float a = x * 2.88539008177792681472f;       // 2*log2(e)
#if __has_builtin(__builtin_amdgcn_exp2f)
  float e = __builtin_amdgcn_exp2f(a);
#else
  float e = exp2f(a);
#endif
  float r = __builtin_amdgcn_rcpf(e + 1.0f);
  return fmaf(-2.0f, r, 1.0f);
}

// ---------------- K1: RNG (threefry partitionable mode) ----------------
__global__ void __launch_bounds__(256) rng_kernel(const float* __restrict__ x0,
                                                  float* __restrict__ A,
                                                  double* __restrict__ A64,
                                                  float* __restrict__ U) {
  const uint32_t t = blockIdx.x;
  const int tid = threadIdx.x;
  uint2 kt = tf2x32(0u, 1u, 0u, t);
  uint2 kn = tf2x32(kt.x, kt.y, 0u, 0u);
  uint2 e0 = tf2x32(kn.x, kn.y, 0u, (uint32_t)tid);
  uint2 e1 = tf2x32(kn.x, kn.y, 0u, (uint32_t)(tid + 256));
  float n0 = normal_from_bits(e0.x ^ e0.y) * 0.1f;
  float n1 = normal_from_bits(e1.x ^ e1.y) * 0.1f;
  float* Arow = A + (size_t)(t + 1) * DDIM;
  Arow[tid]       = n0;
  Arow[tid + 256] = n1;
  if (A64) {
    double* Arow64 = A64 + (size_t)(t + 1) * DDIM;
    Arow64[tid]       = (double)n0;
    Arow64[tid + 256] = (double)n1;
  }
  if (tid == 0) {
    uint2 ku = tf2x32(kt.x, kt.y, 0u, 1u);
    uint2 eu = tf2x32(ku.x, ku.y, 0u, 0u);
    U[t] = __uint_as_float(0x3f800000u | ((eu.x ^ eu.y) >> 9)) - 1.0f;
  }
  if (t == 0) {
    float xv0 = x0[tid], xv1 = x0[tid + 256];
    A[tid]       = xv0;
    A[tid + 256] = xv1;
    if (A64) {
      A64[tid]       = (double)xv0;
      A64[tid + 256] = (double)xv1;
    }
  }
}

// ---------------- K2a: Z = A64 @ W1 (f64, cvt-free), 546 blocks ------------
// 4 rows x 2 cols per thread; same per-row association as R13 -> Z bits
// identical. 546 blocks ~ 2.1/CU co-resident: halves tail imbalance.
__global__ void __launch_bounds__(512) gemm64_kernel(
    const double* __restrict__ A64, const float* __restrict__ W1,
    float* __restrict__ Z, int nrows) {
  const int r0 = blockIdx.x * 4;
  const int t  = threadIdx.x;          // 0..511
  const int c0 = t, c1 = t + 512;
  double acc[4][2];
#pragma unroll
  for (int r = 0; r < 4; ++r) { acc[r][0] = 0.0; acc[r][1] = 0.0; }
  for (int d = 0; d < 512; d += 4) {
    double wA[4], wB[4];
#pragma unroll
    for (int j = 0; j < 4; ++j) {
      wA[j] = (double)W1[(size_t)(d + j) * 1024 + c0];
      wB[j] = (double)W1[(size_t)(d + j) * 1024 + c1];
    }
#pragma unroll
    for (int r = 0; r < 4; ++r) {
      int rr = r0 + r; if (rr >= nrows) rr = nrows - 1;   // uniform clamp
      const double2 a01 = *(const double2*)(A64 + (size_t)rr * 512 + d);
      const double2 a23 = *(const double2*)(A64 + (size_t)rr * 512 + d + 2);
      acc[r][0] += (a01.x * wA[0] + a01.y * wA[1]) +
                   (a23.x * wA[2] + a23.y * wA[3]);
      acc[r][1] += (a01.x * wB[0] + a01.y * wB[1]) +
                   (a23.x * wB[2] + a23.y * wB[3]);
    }
  }
  const int rmax = (nrows - r0 < 4) ? (nrows - r0) : 4;
  for (int r = 0; r < rmax; ++r) {
    Z[(size_t)(r0 + r) * 1024 + c0] = (float)acc[r][0];
    Z[(size_t)(r0 + r) * 1024 + c1] = (float)acc[r][1];
  }
}

// ---------------- K2b: fallback gemm (convert-at-use) ----------------------
__global__ void __launch_bounds__(512) gemm_kernel(const float* __restrict__ A,
                                                   const float* __restrict__ W1,
                                                   float* __restrict__ Z,
                                                   int nrows) {
  const int r0 = blockIdx.x * 4;
  const int t  = threadIdx.x;
  const int c0 = t, c1 = t + 512;
  double acc[4][2];
#pragma unroll
  for (int r = 0; r < 4; ++r) { acc[r][0] = 0.0; acc[r][1] = 0.0; }
  for (int d = 0; d < 512; d += 4) {
    double wA[4], wB[4];
#pragma unroll
    for (int j = 0; j < 4; ++j) {
      wA[j] = (double)W1[(size_t)(d + j) * 1024 + c0];
      wB[j] = (double)W1[(size_t)(d + j) * 1024 + c1];
    }
#pragma unroll
    for (int r = 0; r < 4; ++r) {
      int rr = r0 + r; if (rr >= nrows) rr = nrows - 1;
      const float4 a4 = *(const float4*)(A + (size_t)rr * 512 + d);
      double a0 = (double)a4.x, a1 = (double)a4.y;
      double a2 = (double)a4.z, a3 = (double)a4.w;
      acc[r][0] += (a0 * wA[0] + a1 * wA[1]) + (a2 * wA[2] + a3 * wA[3]);
      acc[r][1] += (a0 * wB[0] + a1 * wB[1]) + (a2 * wB[2] + a3 * wB[3]);
    }
  }
  const int rmax = (nrows - r0 < 4) ? (nrows - r0) : 4;
  for (int r = 0; r < rmax; ++r) {
    Z[(size_t)(r0 + r) * 1024 + c0] = (float)acc[r][0];
    Z[(size_t)(r0 + r) * 1024 + c1] = (float)acc[r][1];
  }
}

// ---------------- DPP wave64 sum-reduce (result in lane 63) ----------------
#define DPP_ADD(v, ctrl)                                                     \
  v += __int_as_float(__builtin_amdgcn_update_dpp(                           \
      0, __float_as_int(v), (ctrl), 0xF, 0xF, true))

__device__ __forceinline__ float wave_reduce_to_last(float v) {
  DPP_ADD(v, 0xB1);   // quad_perm xor1
  DPP_ADD(v, 0x4E);   // quad_perm xor2
  DPP_ADD(v, 0x141);  // row_half_mirror
  DPP_ADD(v, 0x140);  // row_mirror -> row16 totals
  DPP_ADD(v, 0x142);  // row_bcast15
  DPP_ADD(v, 0x143);  // row_bcast31 -> lane 63 wave total
  return v;
}

// Execution barrier with LDS-visibility only (no vmcnt drain).
#define BAR() asm volatile("s_waitcnt lgkmcnt(0)\n\ts_barrier" ::: "memory")

// ---------------- K3: 2-steps-per-barrier chain + fillers ------------------
__global__ void __launch_bounds__(256) chain_kernel(
    const float* __restrict__ Z, const float* __restrict__ A,
    const float* __restrict__ U, const float* __restrict__ x0,
    const float* __restrict__ b1, const float* __restrict__ W2,
    const float* __restrict__ b2, float* __restrict__ out,
    unsigned* __restrict__ flag) {
  const int tid = threadIdx.x;

  if (blockIdx.x != 0) {
    // DVFS keeper: bounded latency-bound fma spin; exits on flag.
    float acc = (float)tid * 1.0e-6f;
    for (int i = 0; i < 4000; ++i) {
#pragma unroll
      for (int jj = 0; jj < 256; ++jj) acc = fmaf(acc, 0.99999988f, 1.0e-7f);
      unsigned f = __hip_atomic_load(flag, __ATOMIC_RELAXED,
                                     __HIP_MEMORY_SCOPE_AGENT);
      if (f == DONE_FLAG) break;
    }
    if (acc == 123456.75f && tid == 1023) out[0] = acc;  // never true
    return;
  }

  const int lane = tid & 63;
  const int wid = tid >> 6;
  __shared__ __align__(16) float wsum[2][3][4];
  __shared__ float Uld[2184];

  const float4* Zv = (const float4*)Z;   // 256 float4 per H-row
  const float2* Av = (const float2*)A;   // 256 float2 per D-row

  for (int i = tid; i < 2184; i += 256) Uld[i] = U[i];

  const float4 w2v = ((const float4*)W2)[tid];
  const float4 b1v = ((const float4*)b1)[tid];
  const float b2v = b2[0];

  float4 z0r = Zv[tid];
  float4 z1r = Zv[256 + tid];
  float4 z2r = Zv[512 + tid];
  float4 zA0 = Zv[3 * 256 + tid], zB0 = Zv[4 * 256 + tid];
  float4 zA1 = Zv[5 * 256 + tid], zB1 = Zv[6 * 256 + tid];
  float2 dAa0 = Av[1 * 256 + tid], dAb0 = Av[2 * 256 + tid];
  float2 dAa1 = Av[3 * 256 + tid], dAb1 = Av[4 * 256 + tid];

  double Y0 = (double)z0r.x + (double)b1v.x;
  double Y1 = (double)z0r.y + (double)b1v.y;
  double Y2 = (double)z0r.z + (double)b1v.z;
  double Y3 = (double)z0r.w + (double)b1v.w;

  float xa = x0[2 * tid], xb = x0[2 * tid + 1];

  __syncthreads();

  {
    float g0 = tanh_fast((float)Y0);
    float g1 = tanh_fast((float)Y1);
    float g2 = tanh_fast((float)Y2);
    float g3 = tanh_fast((float)Y3);
    float tm = fmaf(g3, w2v.w, fmaf(g2, w2v.z, fmaf(g1, w2v.y, g0 * w2v.x)));
    tm = wave_reduce_to_last(tm);
    if (lane == 63) wsum[1][0][wid] = tm;
  }
  __syncthreads();
  float p;
  {
    const float4 pp = *(const float4*)wsum[1][0];
    float m0 = ((pp.x + pp.y) + (pp.z + pp.w)) + b2v;
    p = m0 * m0;
  }
  float um1 = Uld[0] * (p + 1e-12f);
  float u2c = Uld[1];

  double Ya0 = Y0 + (double)z1r.x, Ya1 = Y1 + (double)z1r.y;
  double Ya2 = Y2 + (double)z1r.z, Ya3 = Y3 + (double)z1r.w;
  double Yb0 = Y0 + (double)z2r.x, Yb1 = Y1 + (double)z2r.y;
  double Yb2 = Y2 + (double)z2r.z, Yb3 = Y3 + (double)z2r.w;
  double Yc0 = Ya0 + (double)z2r.x, Yc1 = Ya1 + (double)z2r.y;
  double Yc2 = Ya2 + (double)z2r.z, Yc3 = Ya3 + (double)z2r.w;
  {
    float a0 = tanh_fast((float)Ya0), a1 = tanh_fast((float)Ya1);
    float a2 = tanh_fast((float)Ya2), a3 = tanh_fast((float)Ya3);
    float b0 = tanh_fast((float)Yb0), b1_ = tanh_fast((float)Yb1);
    float b2_ = tanh_fast((float)Yb2), b3 = tanh_fast((float)Yb3);
    float c0 = tanh_fast((float)Yc0), c1 = tanh_fast((float)Yc1);
    float c2 = tanh_fast((float)Yc2), c3 = tanh_fast((float)Yc3);
    float tA = fmaf(a3, w2v.w, fmaf(a2, w2v.z, fmaf(a1, w2v.y, a0 * w2v.x)));
    float tB = fmaf(b3, w2v.w, fmaf(b2_, w2v.z, fmaf(b1_, w2v.y, b0 * w2v.x)));
    float tC = fmaf(c3, w2v.w, fmaf(c2, w2v.z, fmaf(c1, w2v.y, c0 * w2v.x)));
    tA = wave_reduce_to_last(tA);
    tB = wave_reduce_to_last(tB);
    tC = wave_reduce_to_last(tC);
    if (lane == 63) {
      wsum[0][0][wid] = tA;
      wsum[0][1][wid] = tB;
      wsum[0][2][wid] = tC;
    }
  }
  __syncthreads();

#define ITER(k, PAR, ZAB, ZBB, DAB, DBB)                                     \
  {                                                                          \
    float u1n = Uld[2 * (k) + 2];                                            \
    float u2n = Uld[2 * (k) + 3];                                            \
    const float4 e1 = *(const float4*)wsum[PAR][0];                          \
    const float4 e2 = *(const float4*)wsum[PAR][1];                          \
    const float4 e3 = *(const float4*)wsum[PAR][2];                          \
    float m1 = ((e1.x + e1.y) + (e1.z + e1.w)) + b2v;                        \
    float q1 = m1 * m1;                                                      \
    bool a1v = um1 < q1;                                                     \
    float p1 = a1v ? q1 : p;                                                 \
    float um2 = u2c * (p1 + 1e-12f);                                         \
    float m2v = ((e2.x + e2.y) + (e2.z + e2.w)) + b2v;                       \
    float m3v = ((e3.x + e3.y) + (e3.z + e3.w)) + b2v;                       \
    float m23 = a1v ? m3v : m2v;                                             \
    float q23 = m23 * m23;                                                   \
    bool a2v = um2 < q23;                                                    \
    p = a2v ? q23 : p1;                                                      \
    float xat = a1v ? xa + DAB.x : xa;                                       \
    float xbt = a1v ? xb + DAB.y : xb;                                       \
    xa = a2v ? xat + DBB.x : xat;                                            \
    xb = a2v ? xbt + DBB.y : xbt;                                            \
    if ((k) >= 64) {                                                         \
      float2 o1; o1.x = xat; o1.y = xbt;                                     \
      *(float2*)(out + (size_t)(2 * (k) - NBURN) * DDIM + 2 * tid) = o1;     \
      float2 o2; o2.x = xa; o2.y = xb;                                       \
      *(float2*)(out + (size_t)(2 * (k) + 1 - NBURN) * DDIM + 2 * tid) = o2; \
    }                                                                        \
    DAB = Av[(size_t)(2 * (k) + 5) * 256 + tid];                             \
    DBB = Av[(size_t)(2 * (k) + 6) * 256 + tid];                             \
    Y0 = a1v ? (a2v ? Yc0 : Ya0) : (a2v ? Yb0 : Y0);                         \
    Y1 = a1v ? (a2v ? Yc1 : Ya1) : (a2v ? Yb1 : Y1);                         \
    Y2 = a1v ? (a2v ? Yc2 : Ya2) : (a2v ? Yb2 : Y2);                         \
    Y3 = a1v ? (a2v ? Yc3 : Ya3) : (a2v ? Yb3 : Y3);                         \
    Ya0 = Y0 + (double)ZAB.x;  Ya1 = Y1 + (double)ZAB.y;                     \
    Ya2 = Y2 + (double)ZAB.z;  Ya3 = Y3 + (double)ZAB.w;                     \
    Yb0 = Y0 + (double)ZBB.x;  Yb1 = Y1 + (double)ZBB.y;                     \
    Yb2 = Y2 + (double)ZBB.z;  Yb3 = Y3 + (double)ZBB.w;                     \
    Yc0 = Ya0 + (double)ZBB.x; Yc1 = Ya1 + (double)ZBB.y;                    \
    Yc2 = Ya2 + (double)ZBB.z; Yc3 = Ya3 + (double)ZBB.w;                    \
    ZAB = Zv[(size_t)(2 * (k) + 7) * 256 + tid];                             \
    ZBB = Zv[(size_t)(2 * (k) + 8) * 256 + tid];                             \
    float ga0 = tanh_fast((float)Ya0), ga1 = tanh_fast((float)Ya1);          \
    float ga2 = tanh_fast((float)Ya2), ga3 = tanh_fast((float)Ya3);          \
    float gb0 = tanh_fast((float)Yb0), gb1 = tanh_fast((float)Yb1);          \
    float gb2 = tanh_fast((float)Yb2), gb3 = tanh_fast((float)Yb3);          \
    float gc0 = tanh_fast((float)Yc0), gc1 = tanh_fast((float)Yc1);          \
    float gc2 = tanh_fast((float)Yc2), gc3 = tanh_fast((float)Yc3);          \
    float tA = fmaf(ga3, w2v.w, fmaf(ga2, w2v.z, fmaf(ga1, w2v.y, ga0 * w2v.x))); \
    float tB = fmaf(gb3, w2v.w, fmaf(gb2, w2v.z, fmaf(gb1, w2v.y, gb0 * w2v.x))); \
    float tC = fmaf(gc3, w2v.w, fmaf(gc2, w2v.z, fmaf(gc1, w2v.y, gc0 * w2v.x))); \
    tA = wave_reduce_to_last(tA);                                            \
    tB = wave_reduce_to_last(tB);                                            \
    tC = wave_reduce_to_last(tC);                                            \
    if (lane == 63) {                                                        \
      wsum[(PAR) ^ 1][0][wid] = tA;                                          \
      wsum[(PAR) ^ 1][1][wid] = tB;                                          \
      wsum[(PAR) ^ 1][2][wid] = tC;                                          \
    }                                                                        \
    um1 = u1n * (p + 1e-12f);                                                \
    u2c = u2n;                                                               \
    BAR();                                                                   \
  }

  for (int k = 0; k < NITER; k += 2) {
    ITER(k,     0, zA0, zB0, dAa0, dAb0);
    ITER(k + 1, 1, zA1, zB1, dAa1, dAb1);
  }
#undef ITER

  if (tid == 0) {
    __hip_atomic_store(flag, DONE_FLAG, __ATOMIC_RELAXED,
                       __HIP_MEMORY_SCOPE_AGENT);
  }
}

extern "C" void kernel_launch(void* const* d_in, const int* in_sizes, int n_in,
                              void* d_out, int out_size, void* d_ws, size_t ws_size,
                              hipStream_t stream) {
  const float* x0 = (const float*)d_in[0];
  const float* W1 = (const float*)d_in[1];
  const float* b1 = (const float*)d_in[2];
  const float* W2 = (const float*)d_in[3];
  const float* b2 = (const float*)d_in[4];
  float* out = (float*)d_out;

  char* ws = (char*)d_ws;
  // Layout: A (2184x512 f32 = 4,472,832 B) | Z (2184x1024 f32 = 8,945,664 B)
  //       | U (2184 f32 = 8,736 B) | flag (4 B) | pad | A64 (2184x512 f64).
  float* A = (float*)ws;
  float* Z = (float*)(ws + 4472832);
  float* U = (float*)(ws + 4472832 + 8945664);
  unsigned* flag = (unsigned*)(ws + 4472832 + 8945664 + 8736);
  size_t a64_off = 13427328;               // 16-byte aligned
  double* A64 = (double*)(ws + a64_off);
  bool use64 = (ws_size >= a64_off + (size_t)2184 * 512 * 8);

  rng_kernel<<<T_TOTAL, 256, 0, stream>>>(x0, A, use64 ? A64 : (double*)nullptr, U);
  if (use64)
    gemm64_kernel<<<546, 512, 0, stream>>>(A64, W1, Z, NROWS);
  else
    gemm_kernel<<<546, 512, 0, stream>>>(A, W1, Z, NROWS);
  chain_kernel<<<256, 256, 0, stream>>>(Z, A, U, x0, b1, W2, b2, out, flag);
}